// Round 12
// baseline (393.233 us; speedup 1.0000x reference)
//
#include <hip/hip_runtime.h>
#include <math.h>

#define HH 512
#define FF 2048
#define BB 16
#define SS 2048
#define MM 32768  // BB*SS

using f32x4 = __attribute__((ext_vector_type(4))) float;
using s16x8 = __attribute__((ext_vector_type(8))) short;

struct __align__(8)  US4 { unsigned short x, y, z, w; };
struct __align__(16) US8 { unsigned short s[8]; };

__device__ __forceinline__ unsigned short f2bf(float f) {
  unsigned int u = __builtin_bit_cast(unsigned int, f);
  u += 0x7fffu + ((u >> 16) & 1u);
  return (unsigned short)(u >> 16);
}
__device__ __forceinline__ float bf2f(unsigned short u) {
  unsigned int x = ((unsigned int)u) << 16;
  return __builtin_bit_cast(float, x);
}
__device__ __forceinline__ void gload_lds16(const void* g, void* l) {
  __builtin_amdgcn_global_load_lds(
      (const __attribute__((address_space(1))) unsigned int*)g,
      (__attribute__((address_space(3))) unsigned int*)l, 16, 0, 0);
}

// ---- weight conversions (merged) ----
__global__ void k_conv(const float* __restrict__ We, const float* __restrict__ Wa,
                       unsigned short* __restrict__ OWe, unsigned short* __restrict__ OWa) {
  int bid = blockIdx.x, t = threadIdx.x;
  if (bid < 1024) {
    int idx = bid * 256 + t;  // < 262144
    f32x4 x = *(const f32x4*)(We + (size_t)idx * 4);
    US4 p{f2bf(x.x), f2bf(x.y), f2bf(x.z), f2bf(x.w)};
    *(US4*)(OWe + (size_t)idx * 4) = p;
  } else {
    int idx = (bid - 1024) * 256 + t;  // < 65536
    int k = idx >> 7, h4 = idx & 127;
    f32x4 x = *(const f32x4*)(Wa + (size_t)k * 1024 + 512 + h4 * 4);
    US4 p{f2bf(x.x), f2bf(x.y), f2bf(x.z), f2bf(x.w)};
    *(US4*)(OWa + (size_t)idx * 4) = p;
  }
}

// ---- h = hidden[-1] @ Wh.T + bh ----
__global__ void k_h(const float* __restrict__ hidden, const float* __restrict__ Wh,
                    const float* __restrict__ bh, float* __restrict__ h_ws) {
  int t = threadIdx.x, lane = t & 63, wid = t >> 6;
  int out = blockIdx.x * 4 + wid;  // < 8192
  int b = out >> 9, j = out & 511;
  const float* hr = hidden + (1) * BB * FF + b * FF;
  const float* wr = Wh + (size_t)j * FF;
  float a = 0.f;
#pragma unroll
  for (int i = 0; i < 8; ++i) {
    int o = i * 256 + lane * 4;
    f32x4 x = *(const f32x4*)(hr + o);
    f32x4 y = *(const f32x4*)(wr + o);
    a += x.x * y.x + x.y * y.y + x.z * y.z + x.w * y.w;
  }
#pragma unroll
  for (int m = 32; m; m >>= 1) a += __shfl_xor(a, m);
  if (lane == 0) h_ws[out] = a + bh[j];
}

// ---- bb[b][k] = ba[k] + h[b] . Wa[k, 0:512] ----
__global__ void k_bb(const float* __restrict__ h_ws, const float* __restrict__ Wa,
                     const float* __restrict__ ba, float* __restrict__ bb_ws) {
  int t = threadIdx.x, lane = t & 63, wid = t >> 6;
  int out = blockIdx.x * 4 + wid;  // < 8192
  int b = out >> 9, k = out & 511;
  const float* hr = h_ws + b * HH;
  const float* wa = Wa + (size_t)k * 1024;
  float a = 0.f;
#pragma unroll
  for (int i = 0; i < 2; ++i) {
    int o = i * 256 + lane * 4;
    f32x4 x = *(const f32x4*)(hr + o);
    f32x4 y = *(const f32x4*)(wa + o);
    a += x.x * y.x + x.y * y.y + x.z * y.z + x.w * y.w;
  }
#pragma unroll
  for (int m = 32; m; m >>= 1) a += __shfl_xor(a, m);
  if (lane == 0) bb_ws[out] = a + ba[k];
}

// ====== fused GEMM1 + GEMM2 + scores: BM=128, B double-buffered gload_lds ======
// 256 blocks (1/CU), 512 thr / 8 waves, wave-tile 128x64, BK=64, 32 K-steps.
// LDS 144KB: As 16K @0 (single) | Bs0 64K @16K | Bs1 64K @80K.
// Step s: issue B(s+1)->BsN (8 gload_lds) + A(s+2)->regs; compute As x Bs(s)
// (64 MFMA/wave); lgkm-barrier; ds_write A(s+1) (regs from step s-1);
// vmcnt(4) lgkm-barrier  [B(s+1) landed, A(s+2)'s 4 loads stay in flight].
// No vmcnt(0) drain in the loop: B gets a FULL compute phase of latency cover
// (the R5-R10 structures waited B within its own issue phase).
// Layouts (R10-proven subtiled, conflict-free, linear gload dests):
//   A: byte=(kb*8+row/16)*256+(row%16)*16, kb=k>>3 (0..7)
//   B: byte=(kb*32+row/16)*256+(row%16)*16
template<int PAR, bool STB, bool LDA, bool WRA, int VM>
__device__ __forceinline__ void stepB(
    const float* apA, const float* apB, const unsigned short* Web, char* smem,
    int kt, int t, int lane, int wid, int aDst0, int aDst1,
    const int* bRow, const int* bKb,
    f32x4& l0, f32x4& l1, f32x4& l2, f32x4& l3,
    const f32x4& w0, const f32x4& w1, const f32x4& w2, const f32x4& w3,
    f32x4 (&acc)[8][4]) {
  char* BsC = smem + 16384 + (PAR << 16);
  char* BsN = smem + 16384 + ((PAR ^ 1) << 16);
  if (STB) {
#pragma unroll
    for (int i = 0; i < 8; ++i) {
      int idx = i * 512 + t;
      gload_lds16(Web + (size_t)bRow[i] * FF + (kt + 64) + bKb[i] * 8, BsN + idx * 16);
    }
  }
  __builtin_amdgcn_sched_barrier(0);  // pin issue order: B first, then A (vmcnt ledger)
  if (LDA) {
    l0 = *(const f32x4*)(apA + kt + 128);
    l1 = *(const f32x4*)(apA + kt + 132);
    l2 = *(const f32x4*)(apB + kt + 128);
    l3 = *(const f32x4*)(apB + kt + 132);
  }
  __builtin_amdgcn_sched_barrier(0);
#pragma unroll
  for (int ks = 0; ks < 2; ++ks) {
    s16x8 bfr[4];
#pragma unroll
    for (int ni = 0; ni < 4; ++ni)
      bfr[ni] = *(const s16x8*)(BsC + ((ks * 4 + (lane >> 4)) * 32 + wid * 4 + ni) * 256 + ((lane & 15) << 4));
#pragma unroll
    for (int mi = 0; mi < 8; ++mi) {
      s16x8 af = *(const s16x8*)(smem + ((ks * 4 + (lane >> 4)) * 8 + mi) * 256 + ((lane & 15) << 4));
#pragma unroll
      for (int ni = 0; ni < 4; ++ni)
        acc[mi][ni] = __builtin_amdgcn_mfma_f32_16x16x32_bf16(af, bfr[ni], acc[mi][ni], 0, 0, 0);
    }
  }
  asm volatile("s_waitcnt lgkmcnt(0)" ::: "memory");
  __builtin_amdgcn_s_barrier();
  __builtin_amdgcn_sched_barrier(0);
  if (WRA) {
    US8 oa{f2bf(w0.x), f2bf(w0.y), f2bf(w0.z), f2bf(w0.w),
           f2bf(w1.x), f2bf(w1.y), f2bf(w1.z), f2bf(w1.w)};
    *(US8*)(smem + aDst0) = oa;
    US8 ob{f2bf(w2.x), f2bf(w2.y), f2bf(w2.z), f2bf(w2.w),
           f2bf(w3.x), f2bf(w3.y), f2bf(w3.z), f2bf(w3.w)};
    *(US8*)(smem + aDst1) = ob;
  }
  asm volatile("s_waitcnt vmcnt(%0) lgkmcnt(0)" :: "i"(VM) : "memory");
  __builtin_amdgcn_s_barrier();
  __builtin_amdgcn_sched_barrier(0);
}

__global__ __launch_bounds__(512, 2) void k_gemm1f(
    const float* __restrict__ enc, const unsigned short* __restrict__ Web,
    const float* __restrict__ be, const unsigned short* __restrict__ Waeb,
    const float* __restrict__ bbw, const float* __restrict__ vv,
    unsigned short* __restrict__ eo, float* __restrict__ sp) {
  __shared__ char smem[147456];  // 144 KB
  const int t = threadIdx.x, lane = t & 63, wid = t >> 6;
  const int m0 = blockIdx.x * 128;
  const float* enc_m0 = enc + (size_t)m0 * FF;
  f32x4 acc[8][4] = {};

  // A staging: cells (row=t&127, kb=t>>7) and (row, kb+4)
  const int aRow = t & 127;
  const int aKb0 = t >> 7;  // 0..3
  const int aDst0 = ((aKb0 * 8 + (aRow >> 4)) << 8) + ((aRow & 15) << 4);
  const int aDst1 = (((aKb0 + 4) * 8 + (aRow >> 4)) << 8) + ((aRow & 15) << 4);
  const float* apA = enc_m0 + (size_t)aRow * FF + aKb0 * 8;
  const float* apB = apA + 32;

  // B staging coords: 8 cells/thread
  int bRow[8], bKb[8];
#pragma unroll
  for (int i = 0; i < 8; ++i) {
    int idx = i * 512 + t;
    bRow[i] = ((idx >> 4) & 31) * 16 + (idx & 15);
    bKb[i]  = idx >> 9;  // 0..7
  }

  // ---- prologue: B(0)->Bs0; A(0)->As; A(1)->X regs; full drain ----
  f32x4 X0, X1, X2, X3, Y0, Y1, Y2, Y3;
#pragma unroll
  for (int i = 0; i < 8; ++i) {
    int idx = i * 512 + t;
    gload_lds16(Web + (size_t)bRow[i] * FF + bKb[i] * 8, smem + 16384 + idx * 16);
  }
  {
    f32x4 a0 = *(const f32x4*)(apA);
    f32x4 a1 = *(const f32x4*)(apA + 4);
    f32x4 a2 = *(const f32x4*)(apB);
    f32x4 a3 = *(const f32x4*)(apB + 4);
    US8 oa{f2bf(a0.x), f2bf(a0.y), f2bf(a0.z), f2bf(a0.w),
           f2bf(a1.x), f2bf(a1.y), f2bf(a1.z), f2bf(a1.w)};
    *(US8*)(smem + aDst0) = oa;
    US8 ob{f2bf(a2.x), f2bf(a2.y), f2bf(a2.z), f2bf(a2.w),
           f2bf(a3.x), f2bf(a3.y), f2bf(a3.z), f2bf(a3.w)};
    *(US8*)(smem + aDst1) = ob;
    X0 = *(const f32x4*)(apA + 64);
    X1 = *(const f32x4*)(apA + 68);
    X2 = *(const f32x4*)(apB + 64);
    X3 = *(const f32x4*)(apB + 68);
  }
  asm volatile("s_waitcnt vmcnt(0) lgkmcnt(0)" ::: "memory");
  __builtin_amdgcn_s_barrier();
  __builtin_amdgcn_sched_barrier(0);

  // ---- main loop: s = 0..29 (paired), tail 30, 31 ----
#pragma unroll 1
  for (int it = 0; it < 15; ++it) {
    int kt = it << 7;
    // s even: load A(s+2)->Y, write A(s+1) from X
    stepB<0, true, true, true, 4>(apA, apB, Web, smem, kt, t, lane, wid, aDst0, aDst1,
                                  bRow, bKb, Y0, Y1, Y2, Y3, X0, X1, X2, X3, acc);
    // s odd: load A(s+3)->X, write A(s+2) from Y
    stepB<1, true, true, true, 4>(apA, apB, Web, smem, kt + 64, t, lane, wid, aDst0, aDst1,
                                  bRow, bKb, X0, X1, X2, X3, Y0, Y1, Y2, Y3, acc);
  }
  // s=30: stage B(31); no A load; write A(31) from X (loaded at s=29)
  stepB<0, true, false, true, 0>(apA, apB, Web, smem, 1920, t, lane, wid, aDst0, aDst1,
                                 bRow, bKb, Y0, Y1, Y2, Y3, X0, X1, X2, X3, acc);
  // s=31: compute only
  stepB<1, false, false, false, 0>(apA, apB, Web, smem, 1984, t, lane, wid, aDst0, aDst1,
                                   bRow, bKb, X0, X1, X2, X3, Y0, Y1, Y2, Y3, acc);

  // ---- epilogue: two 64-row passes; Cs 64KB aliases Bs0 @16K ----
  unsigned short* Cs = (unsigned short*)(smem + 16384);  // [64][512] bf16, byte = r*1024 + ((c*2)^((r&7)<<4))
  const int b = m0 >> 11;
#pragma unroll 1
  for (int h = 0; h < 2; ++h) {
#pragma unroll
    for (int ni = 0; ni < 4; ++ni) {
      int col = wid * 64 + ni * 16 + (lane & 15);
      float bev = be[col];
#pragma unroll
      for (int mi = 0; mi < 4; ++mi)
#pragma unroll
        for (int j = 0; j < 4; ++j) {
          int row = mi * 16 + (lane >> 4) * 4 + j;
          int byte = row * 1024 + ((col * 2) ^ ((row & 7) << 4));
          *(unsigned short*)((char*)Cs + byte) = f2bf(acc[4 * h + mi][ni][j] + bev);
        }
    }
    __syncthreads();
    // eo store (de-swizzled US8 reads)
#pragma unroll
    for (int i = 0; i < 8; ++i) {
      int idx = i * 512 + t, row = idx >> 6, c = idx & 63;
      int byte = row * 1024 + ((c * 16) ^ ((row & 7) << 4));
      *(US8*)(eo + (size_t)(m0 + 64 * h + row) * HH + c * 8) = *(const US8*)((const char*)Cs + byte);
    }
    // GEMM2: E(64x64/wave) = CsTile @ Waeb^T (B from L2), fully unrolled
    f32x4 acc2[4][4] = {};
#pragma unroll
    for (int kt2 = 0; kt2 < HH; kt2 += 64) {
#pragma unroll
      for (int ks = 0; ks < 2; ++ks) {
        int k2 = kt2 + ks * 32 + (lane >> 4) * 8;
        s16x8 af[4], bfr[4];
#pragma unroll
        for (int mi = 0; mi < 4; ++mi) {
          int row = mi * 16 + (lane & 15);
          int byte = row * 1024 + ((k2 * 2) ^ ((row & 7) << 4));
          af[mi] = *(const s16x8*)((const char*)Cs + byte);
        }
#pragma unroll
        for (int ni = 0; ni < 4; ++ni) {
          int nrow = wid * 64 + ni * 16 + (lane & 15);
          bfr[ni] = *(const s16x8*)(Waeb + (size_t)nrow * HH + k2);
        }
#pragma unroll
        for (int mi = 0; mi < 4; ++mi)
#pragma unroll
          for (int ni = 0; ni < 4; ++ni)
            acc2[mi][ni] = __builtin_amdgcn_mfma_f32_16x16x32_bf16(af[mi], bfr[ni], acc2[mi][ni], 0, 0, 0);
      }
    }
    // scores = sum_n tanh(E + bb) * v
    float vcol[4], bcol[4];
#pragma unroll
    for (int ni = 0; ni < 4; ++ni) {
      int col = wid * 64 + ni * 16 + (lane & 15);
      vcol[ni] = vv[col];
      bcol[ni] = bbw[b * HH + col];
    }
    float ps[4][4];
#pragma unroll
    for (int mi = 0; mi < 4; ++mi)
#pragma unroll
      for (int j = 0; j < 4; ++j) {
        float s = 0.f;
#pragma unroll
        for (int ni = 0; ni < 4; ++ni)
          s += tanhf(acc2[mi][ni][j] + bcol[ni]) * vcol[ni];
        ps[mi][j] = s;
      }
#pragma unroll
    for (int m = 1; m < 16; m <<= 1)
#pragma unroll
      for (int mi = 0; mi < 4; ++mi)
#pragma unroll
        for (int j = 0; j < 4; ++j) ps[mi][j] += __shfl_xor(ps[mi][j], m);
    float* red = (float*)smem;  // As region (dead), 2KB
    if ((lane & 15) == 0) {
#pragma unroll
      for (int mi = 0; mi < 4; ++mi)
#pragma unroll
        for (int j = 0; j < 4; ++j)
          red[wid * 64 + mi * 16 + (lane >> 4) * 4 + j] = ps[mi][j];
    }
    __syncthreads();
    if (t < 64) {
      float s = 0.f;
#pragma unroll
      for (int w = 0; w < 8; ++w) s += red[w * 64 + t];
      sp[m0 + 64 * h + t] = s;
    }
    __syncthreads();  // Cs/red safe to overwrite in next pass
  }
}

// ---- softmax over S per batch ----
__global__ void k_softmax(const float* __restrict__ sp, float* __restrict__ attn) {
  const int b = blockIdx.x, t = threadIdx.x, lane = t & 63, wid = t >> 6;
  __shared__ float red[4];
  float vals[8], lmax = -3.0e38f;
#pragma unroll
  for (int i = 0; i < 8; ++i) {
    float x = sp[b * SS + t + i * 256];
    vals[i] = x;
    lmax = fmaxf(lmax, x);
  }
#pragma unroll
  for (int m = 32; m; m >>= 1) lmax = fmaxf(lmax, __shfl_xor(lmax, m));
  if (lane == 0) red[wid] = lmax;
  __syncthreads();
  lmax = fmaxf(fmaxf(red[0], red[1]), fmaxf(red[2], red[3]));
  __syncthreads();
  float lsum = 0.f;
#pragma unroll
  for (int i = 0; i < 8; ++i) {
    vals[i] = __expf(vals[i] - lmax);
    lsum += vals[i];
  }
#pragma unroll
  for (int m = 32; m; m >>= 1) lsum += __shfl_xor(lsum, m);
  if (lane == 0) red[wid] = lsum;
  __syncthreads();
  float inv = 1.0f / (red[0] + red[1] + red[2] + red[3]);
#pragma unroll
  for (int i = 0; i < 8; ++i) attn[b * SS + t + i * 256] = vals[i] * inv;
}

// ---- context stage 1 ----
__global__ __launch_bounds__(512) void k_ctx1(const unsigned short* __restrict__ eo,
                                              const float* __restrict__ attn,
                                              float* __restrict__ cp) {
  __shared__ float red[8][512];
  const int b = blockIdx.x >> 4, ch = blockIdx.x & 15, t = threadIdx.x;
  const int tg = t & 63, sg = t >> 6;
  const float* aw = attn + b * SS + ch * 128;
  float acc[8] = {};
#pragma unroll 4
  for (int i = 0; i < 16; ++i) {
    int s = sg + i * 8;
    float w = aw[s];
    US8 vv8 = *(const US8*)(eo + (size_t)(b * SS + ch * 128 + s) * HH + tg * 8);
#pragma unroll
    for (int j = 0; j < 8; ++j) acc[j] += w * bf2f(vv8.s[j]);
  }
#pragma unroll
  for (int j = 0; j < 8; ++j) red[sg][tg * 8 + j] = acc[j];
  __syncthreads();
  float a = 0.f;
#pragma unroll
  for (int g = 0; g < 8; ++g) a += red[g][t];
  cp[(size_t)blockIdx.x * HH + t] = a;
}

// ---- context stage 2 ----
__global__ void k_ctx2(const float* __restrict__ cp, float* __restrict__ ctx) {
  const int b = blockIdx.x, h = threadIdx.x;
  float a = 0.f;
#pragma unroll
  for (int c = 0; c < 16; ++c) a += cp[(size_t)(b * 16 + c) * HH + h];
  ctx[b * HH + h] = a;
}

extern "C" void kernel_launch(void* const* d_in, const int* in_sizes, int n_in,
                              void* d_out, int out_size, void* d_ws, size_t ws_size,
                              hipStream_t stream) {
  (void)in_sizes; (void)n_in; (void)out_size; (void)ws_size;
  const float* hidden = (const float*)d_in[0];
  const float* enc    = (const float*)d_in[1];
  const float* We     = (const float*)d_in[2];
  const float* be     = (const float*)d_in[3];
  const float* Wh     = (const float*)d_in[4];
  const float* bh     = (const float*)d_in[5];
  const float* Wa     = (const float*)d_in[6];
  const float* ba     = (const float*)d_in[7];
  const float* v      = (const float*)d_in[8];

  float* out  = (float*)d_out;
  float* ctx  = out;            // 16*512
  float* attn = out + BB * HH;  // 16*2048

  char* ws = (char*)d_ws;
  unsigned short* Web  = (unsigned short*)ws;  ws += (size_t)HH * FF * 2;     // 2 MB
  unsigned short* Waeb = (unsigned short*)ws;  ws += (size_t)HH * HH * 2;     // 512 KB
  float* h_ws  = (float*)ws;                   ws += (size_t)BB * HH * 4;     // 32 KB
  float* bb_ws = (float*)ws;                   ws += (size_t)BB * HH * 4;     // 32 KB
  unsigned short* eo = (unsigned short*)ws;    ws += (size_t)MM * HH * 2;     // 32 MB
  float* sp = (float*)ws;                      ws += (size_t)MM * 4;          // 128 KB
  float* cp = (float*)ws;                      ws += (size_t)BB * 16 * HH * 4;// 512 KB

  k_conv<<<1280, 256, 0, stream>>>(We, Wa, Web, Waeb);
  k_h<<<2048, 256, 0, stream>>>(hidden, Wh, bh, h_ws);
  k_bb<<<2048, 256, 0, stream>>>(h_ws, Wa, ba, bb_ws);
  k_gemm1f<<<256, 512, 0, stream>>>(enc, Web, be, Waeb, bb_ws, v, eo, sp);
  k_softmax<<<16, 256, 0, stream>>>(sp, attn);
  k_ctx1<<<256, 512, 0, stream>>>(eo, attn, cp);
  k_ctx2<<<16, 512, 0, stream>>>(cp, ctx);
}

// Round 13
// 239.714 us; speedup vs baseline: 1.6404x; 1.6404x over previous
//
#include <hip/hip_runtime.h>
#include <math.h>

#define HH 512
#define FF 2048
#define BB 16
#define SS 2048
#define MM 32768  // BB*SS

using f32x4 = __attribute__((ext_vector_type(4))) float;
using s16x8 = __attribute__((ext_vector_type(8))) short;

struct __align__(8)  US4 { unsigned short x, y, z, w; };
struct __align__(16) US8 { unsigned short s[8]; };

__device__ __forceinline__ unsigned short f2bf(float f) {
  unsigned int u = __builtin_bit_cast(unsigned int, f);
  u += 0x7fffu + ((u >> 16) & 1u);
  return (unsigned short)(u >> 16);
}
__device__ __forceinline__ float bf2f(unsigned short u) {
  unsigned int x = ((unsigned int)u) << 16;
  return __builtin_bit_cast(float, x);
}
__device__ __forceinline__ void gload_lds16(const void* g, void* l) {
  __builtin_amdgcn_global_load_lds(
      (const __attribute__((address_space(1))) unsigned int*)g,
      (__attribute__((address_space(3))) unsigned int*)l, 16, 0, 0);
}

// ---- prep: weight conversions + h = hidden[-1] @ Wh.T + bh (merged) ----
__global__ void k_prep(const float* __restrict__ We, const float* __restrict__ Wa,
                       const float* __restrict__ hidden, const float* __restrict__ Wh,
                       const float* __restrict__ bh,
                       unsigned short* __restrict__ OWe, unsigned short* __restrict__ OWa,
                       float* __restrict__ h_ws) {
  int bid = blockIdx.x, t = threadIdx.x;
  if (bid < 1024) {
    int idx = bid * 256 + t;  // < 262144
    f32x4 x = *(const f32x4*)(We + (size_t)idx * 4);
    US4 p{f2bf(x.x), f2bf(x.y), f2bf(x.z), f2bf(x.w)};
    *(US4*)(OWe + (size_t)idx * 4) = p;
  } else if (bid < 1280) {
    int idx = (bid - 1024) * 256 + t;  // < 65536
    int k = idx >> 7, h4 = idx & 127;
    f32x4 x = *(const f32x4*)(Wa + (size_t)k * 1024 + 512 + h4 * 4);
    US4 p{f2bf(x.x), f2bf(x.y), f2bf(x.z), f2bf(x.w)};
    *(US4*)(OWa + (size_t)idx * 4) = p;
  } else {
    int lane = t & 63, wid = t >> 6;
    int out = (bid - 1280) * 4 + wid;  // < 8192
    int b = out >> 9, j = out & 511;
    const float* hr = hidden + (1) * BB * FF + b * FF;
    const float* wr = Wh + (size_t)j * FF;
    float a = 0.f;
#pragma unroll
    for (int i = 0; i < 8; ++i) {
      int o = i * 256 + lane * 4;
      f32x4 x = *(const f32x4*)(hr + o);
      f32x4 y = *(const f32x4*)(wr + o);
      a += x.x * y.x + x.y * y.y + x.z * y.z + x.w * y.w;
    }
#pragma unroll
    for (int m = 32; m; m >>= 1) a += __shfl_xor(a, m);
    if (lane == 0) h_ws[out] = a + bh[j];
  }
}

// ---- bb[b][k] = ba[k] + h[b] . Wa[k, 0:512] ----
__global__ void k_bb(const float* __restrict__ h_ws, const float* __restrict__ Wa,
                     const float* __restrict__ ba, float* __restrict__ bb_ws) {
  int t = threadIdx.x, lane = t & 63, wid = t >> 6;
  int out = blockIdx.x * 4 + wid;  // < 8192
  int b = out >> 9, k = out & 511;
  const float* hr = h_ws + b * HH;
  const float* wa = Wa + (size_t)k * 1024;
  float a = 0.f;
#pragma unroll
  for (int i = 0; i < 2; ++i) {
    int o = i * 256 + lane * 4;
    f32x4 x = *(const f32x4*)(hr + o);
    f32x4 y = *(const f32x4*)(wa + o);
    a += x.x * y.x + x.y * y.y + x.z * y.z + x.w * y.w;
  }
#pragma unroll
  for (int m = 32; m; m >>= 1) a += __shfl_xor(a, m);
  if (lane == 0) bb_ws[out] = a + ba[k];
}

// ====== fused GEMM1 + GEMM2 + scores (R10 base + setprio + K-rotation) ======
// R10 geometry (best: 170.5us total): M=64 x N=512, 512 thr / 8 waves, BK=64,
// single-buffered LDS 72KB => 2 blocks/CU; counted waits (vmcnt(2) at
// barrier1 keeps the 2 A-prefetch loads flying; lgkm-only barrier2).
// R13 deltas: (1) s_setprio(1) around the MFMA cluster (T5: the CU's two
// blocks ping-pong staging/compute; boost the computing block);
// (2) odd blocks rotate K-start by 1024 (decorrelate L2/HBM streams).
__global__ __launch_bounds__(512, 4) void k_gemm1f(
    const float* __restrict__ enc, const unsigned short* __restrict__ Web,
    const float* __restrict__ be, const unsigned short* __restrict__ Waeb,
    const float* __restrict__ bbw, const float* __restrict__ vv,
    unsigned short* __restrict__ eo, float* __restrict__ sp) {
  __shared__ unsigned short smem[36864];  // 72 KB
  unsigned short* As = smem;              // [64][64] swizzled
  unsigned short* Bs = smem + 4096;       // [512][64] swizzled
  const int t = threadIdx.x, lane = t & 63, wid = t >> 6;
  const int m0 = blockIdx.x * 64;
  const int koff = (blockIdx.x & 1) << 10;  // 0 or 1024: K rotation
  const float* enc_m0 = enc + (size_t)m0 * FF;
  f32x4 acc[4][4] = {};

  f32x4 areg[2];
#pragma unroll
  for (int i = 0; i < 2; ++i) {
    int idx = i * 512 + t, row = idx >> 4, c4 = idx & 15;
    areg[i] = *(const f32x4*)(enc_m0 + (size_t)row * FF + koff + c4 * 4);
  }

#pragma unroll 1
  for (int kt = 0; kt < FF; kt += 64) {
    const int kc = (kt + koff) & 2047;            // current rotated K
    const int kn = (kt + 64 + koff) & 2047;       // next rotated K
    // B tile: rows 0..511 of Web, pre-swizzled source chunk -> linear LDS
#pragma unroll
    for (int i = 0; i < 8; ++i) {
      int idx = i * 512 + t, row = idx >> 3, c = idx & 7, sc = c ^ (row & 7);
      gload_lds16(Web + (size_t)row * FF + kc + sc * 8, Bs + idx * 8);
    }
    // A tile: cvt prefetched regs -> swizzled ds_write
#pragma unroll
    for (int i = 0; i < 2; ++i) {
      int idx = i * 512 + t, row = idx >> 4, c4 = idx & 15;
      f32x4 x = areg[i];
      US4 p{f2bf(x.x), f2bf(x.y), f2bf(x.z), f2bf(x.w)};
      int byte = row * 128 + ((c4 * 8) ^ ((row & 7) << 4));
      *(US4*)((char*)As + byte) = p;
    }
    // prefetch next A (stays in flight across the compute phase)
#pragma unroll
    for (int i = 0; i < 2; ++i) {
      int idx = i * 512 + t, row = idx >> 4, c4 = idx & 15;
      areg[i] = *(const f32x4*)(enc_m0 + (size_t)row * FF + kn + c4 * 4);
    }
    // barrier1: B (4 gload_lds) landed; 2 A loads keep flying
    asm volatile("s_waitcnt vmcnt(2) lgkmcnt(0)" ::: "memory");
    __builtin_amdgcn_s_barrier();
    __builtin_amdgcn_sched_barrier(0);
    __builtin_amdgcn_s_setprio(1);
#pragma unroll
    for (int ks = 0; ks < 2; ++ks) {
      s16x8 af[4], bfr[4];
#pragma unroll
      for (int mi = 0; mi < 4; ++mi) {
        int row = mi * 16 + (lane & 15);
        int byte = row * 128 + (((ks * 64) + (lane >> 4) * 16) ^ ((row & 7) << 4));
        af[mi] = *(const s16x8*)((const char*)As + byte);
      }
#pragma unroll
      for (int ni = 0; ni < 4; ++ni) {
        int row = wid * 64 + ni * 16 + (lane & 15);
        int byte = row * 128 + (((ks * 64) + (lane >> 4) * 16) ^ ((row & 7) << 4));
        bfr[ni] = *(const s16x8*)((const char*)Bs + byte);
      }
#pragma unroll
      for (int mi = 0; mi < 4; ++mi)
#pragma unroll
        for (int ni = 0; ni < 4; ++ni)
          acc[mi][ni] = __builtin_amdgcn_mfma_f32_16x16x32_bf16(af[mi], bfr[ni], acc[mi][ni], 0, 0, 0);
    }
    __builtin_amdgcn_s_setprio(0);
    // barrier2: LDS reads retired (lgkm only); A loads still in flight
    asm volatile("s_waitcnt lgkmcnt(0)" ::: "memory");
    __builtin_amdgcn_s_barrier();
    __builtin_amdgcn_sched_barrier(0);
  }

  // ---- epilogue 1: acc (+be) -> swizzled Cs (Bs region, 64KB) ----
  unsigned short* Cs = smem + 4096;  // [64][512] bf16, byte = r*1024 + ((c*2)^((r&7)<<4))
#pragma unroll
  for (int ni = 0; ni < 4; ++ni) {
    int col = wid * 64 + ni * 16 + (lane & 15);
    float bev = be[col];
#pragma unroll
    for (int mi = 0; mi < 4; ++mi)
#pragma unroll
      for (int j = 0; j < 4; ++j) {
        int row = mi * 16 + (lane >> 4) * 4 + j;
        int byte = row * 1024 + ((col * 2) ^ ((row & 7) << 4));
        *(unsigned short*)((char*)Cs + byte) = f2bf(acc[mi][ni][j] + bev);
      }
  }
  __syncthreads();

  // ---- epilogue 2: coalesced eo store (de-swizzled US8 reads) ----
#pragma unroll
  for (int i = 0; i < 8; ++i) {
    int idx = i * 512 + t, row = idx >> 6, c = idx & 63;
    int byte = row * 1024 + ((c * 16) ^ ((row & 7) << 4));
    *(US8*)(eo + (size_t)(m0 + row) * HH + c * 8) = *(const US8*)((const char*)Cs + byte);
  }

  // ---- epilogue 3: GEMM2  E(64x64 per wave) = eoTile @ Waeb^T, full unroll ----
  f32x4 acc2[4][4] = {};
#pragma unroll
  for (int kt2 = 0; kt2 < HH; kt2 += 64) {
#pragma unroll
    for (int ks = 0; ks < 2; ++ks) {
      int k2 = kt2 + ks * 32 + (lane >> 4) * 8;
      s16x8 af[4], bfr[4];
#pragma unroll
      for (int mi = 0; mi < 4; ++mi) {
        int row = mi * 16 + (lane & 15);
        int byte = row * 1024 + ((k2 * 2) ^ ((row & 7) << 4));
        af[mi] = *(const s16x8*)((const char*)Cs + byte);
      }
#pragma unroll
      for (int ni = 0; ni < 4; ++ni) {
        int nrow = wid * 64 + ni * 16 + (lane & 15);
        bfr[ni] = *(const s16x8*)(Waeb + (size_t)nrow * HH + k2);
      }
#pragma unroll
      for (int mi = 0; mi < 4; ++mi)
#pragma unroll
        for (int ni = 0; ni < 4; ++ni)
          acc2[mi][ni] = __builtin_amdgcn_mfma_f32_16x16x32_bf16(af[mi], bfr[ni], acc2[mi][ni], 0, 0, 0);
    }
  }

  // ---- epilogue 4: scores = sum_n tanh(E + bb) * v ----
  const int b = m0 >> 11;
  float vcol[4], bcol[4];
#pragma unroll
  for (int ni = 0; ni < 4; ++ni) {
    int col = wid * 64 + ni * 16 + (lane & 15);
    vcol[ni] = vv[col];
    bcol[ni] = bbw[b * HH + col];
  }
  float ps[4][4];
#pragma unroll
  for (int mi = 0; mi < 4; ++mi)
#pragma unroll
    for (int j = 0; j < 4; ++j) {
      float s = 0.f;
#pragma unroll
      for (int ni = 0; ni < 4; ++ni)
        s += tanhf(acc2[mi][ni][j] + bcol[ni]) * vcol[ni];
      ps[mi][j] = s;
    }
#pragma unroll
  for (int m = 1; m < 16; m <<= 1)
#pragma unroll
    for (int mi = 0; mi < 4; ++mi)
#pragma unroll
      for (int j = 0; j < 4; ++j) ps[mi][j] += __shfl_xor(ps[mi][j], m);
  float* red = (float*)smem;  // 2KB @0 (As region; Cs untouched)
  if ((lane & 15) == 0) {
#pragma unroll
    for (int mi = 0; mi < 4; ++mi)
#pragma unroll
      for (int j = 0; j < 4; ++j)
        red[wid * 64 + mi * 16 + (lane >> 4) * 4 + j] = ps[mi][j];
  }
  __syncthreads();
  if (t < 64) {
    float s = 0.f;
#pragma unroll
    for (int w = 0; w < 8; ++w) s += red[w * 64 + t];
    sp[m0 + t] = s;
  }
}

// ---- softmax over S per batch ----
__global__ void k_softmax(const float* __restrict__ sp, float* __restrict__ attn) {
  const int b = blockIdx.x, t = threadIdx.x, lane = t & 63, wid = t >> 6;
  __shared__ float red[4];
  float vals[8], lmax = -3.0e38f;
#pragma unroll
  for (int i = 0; i < 8; ++i) {
    float x = sp[b * SS + t + i * 256];
    vals[i] = x;
    lmax = fmaxf(lmax, x);
  }
#pragma unroll
  for (int m = 32; m; m >>= 1) lmax = fmaxf(lmax, __shfl_xor(lmax, m));
  if (lane == 0) red[wid] = lmax;
  __syncthreads();
  lmax = fmaxf(fmaxf(red[0], red[1]), fmaxf(red[2], red[3]));
  __syncthreads();
  float lsum = 0.f;
#pragma unroll
  for (int i = 0; i < 8; ++i) {
    vals[i] = __expf(vals[i] - lmax);
    lsum += vals[i];
  }
#pragma unroll
  for (int m = 32; m; m >>= 1) lsum += __shfl_xor(lsum, m);
  if (lane == 0) red[wid] = lsum;
  __syncthreads();
  float inv = 1.0f / (red[0] + red[1] + red[2] + red[3]);
#pragma unroll
  for (int i = 0; i < 8; ++i) attn[b * SS + t + i * 256] = vals[i] * inv;
}

// ---- context stage 1 ----
__global__ __launch_bounds__(512) void k_ctx1(const unsigned short* __restrict__ eo,
                                              const float* __restrict__ attn,
                                              float* __restrict__ cp) {
  __shared__ float red[8][512];
  const int b = blockIdx.x >> 4, ch = blockIdx.x & 15, t = threadIdx.x;
  const int tg = t & 63, sg = t >> 6;
  const float* aw = attn + b * SS + ch * 128;
  float acc[8] = {};
#pragma unroll 4
  for (int i = 0; i < 16; ++i) {
    int s = sg + i * 8;
    float w = aw[s];
    US8 vv8 = *(const US8*)(eo + (size_t)(b * SS + ch * 128 + s) * HH + tg * 8);
#pragma unroll
    for (int j = 0; j < 8; ++j) acc[j] += w * bf2f(vv8.s[j]);
  }
#pragma unroll
  for (int j = 0; j < 8; ++j) red[sg][tg * 8 + j] = acc[j];
  __syncthreads();
  float a = 0.f;
#pragma unroll
  for (int g = 0; g < 8; ++g) a += red[g][t];
  cp[(size_t)blockIdx.x * HH + t] = a;
}

// ---- context stage 2 ----
__global__ void k_ctx2(const float* __restrict__ cp, float* __restrict__ ctx) {
  const int b = blockIdx.x, h = threadIdx.x;
  float a = 0.f;
#pragma unroll
  for (int c = 0; c < 16; ++c) a += cp[(size_t)(b * 16 + c) * HH + h];
  ctx[b * HH + h] = a;
}

extern "C" void kernel_launch(void* const* d_in, const int* in_sizes, int n_in,
                              void* d_out, int out_size, void* d_ws, size_t ws_size,
                              hipStream_t stream) {
  (void)in_sizes; (void)n_in; (void)out_size; (void)ws_size;
  const float* hidden = (const float*)d_in[0];
  const float* enc    = (const float*)d_in[1];
  const float* We     = (const float*)d_in[2];
  const float* be     = (const float*)d_in[3];
  const float* Wh     = (const float*)d_in[4];
  const float* bh     = (const float*)d_in[5];
  const float* Wa     = (const float*)d_in[6];
  const float* ba     = (const float*)d_in[7];
  const float* v      = (const float*)d_in[8];

  float* out  = (float*)d_out;
  float* ctx  = out;            // 16*512
  float* attn = out + BB * HH;  // 16*2048

  char* ws = (char*)d_ws;
  unsigned short* Web  = (unsigned short*)ws;  ws += (size_t)HH * FF * 2;     // 2 MB
  unsigned short* Waeb = (unsigned short*)ws;  ws += (size_t)HH * HH * 2;     // 512 KB
  float* h_ws  = (float*)ws;                   ws += (size_t)BB * HH * 4;     // 32 KB
  float* bb_ws = (float*)ws;                   ws += (size_t)BB * HH * 4;     // 32 KB
  unsigned short* eo = (unsigned short*)ws;    ws += (size_t)MM * HH * 2;     // 32 MB
  float* sp = (float*)ws;                      ws += (size_t)MM * 4;          // 128 KB
  float* cp = (float*)ws;                      ws += (size_t)BB * 16 * HH * 4;// 512 KB

  k_prep<<<3328, 256, 0, stream>>>(We, Wa, hidden, Wh, bh, Web, Waeb, h_ws);
  k_bb<<<2048, 256, 0, stream>>>(h_ws, Wa, ba, bb_ws);
  k_gemm1f<<<512, 512, 0, stream>>>(enc, Web, be, Waeb, bb_ws, v, eo, sp);
  k_softmax<<<16, 256, 0, stream>>>(sp, attn);
  k_ctx1<<<256, 512, 0, stream>>>(eo, attn, cp);
  k_ctx2<<<16, 512, 0, stream>>>(cp, ctx);
}